// Round 5
// baseline (10015.128 us; speedup 1.0000x reference)
//
#include <hip/hip_runtime.h>
#include <math.h>

#define BSZ 512
#define TT  100
#define NDD 10
#define DSS 6
#define INS 256
#define HID 256
#define CAT 2816   // INS*NDD + HID
#define KZ  320
#define NOUTP 320
#define NOUT 266
#define NBLK 256
#define NTHR 1024

typedef short sh8 __attribute__((ext_vector_type(8)));
typedef float f4  __attribute__((ext_vector_type(4)));
typedef unsigned short ushort_t;

__device__ __forceinline__ float sigf(float x) { return 1.0f / (1.0f + expf(-x)); }

__device__ __forceinline__ ushort_t f2bf(float f) {
    union { float f; unsigned int u; } v; v.f = f;
    unsigned int r = (v.u + 0x7FFFu + ((v.u >> 16) & 1u)) >> 16;
    return (ushort_t)r;
}

#define MFMA(a, b, c) __builtin_amdgcn_mfma_f32_16x16x32_bf16((a), (b), (c), 0, 0, 0)
#define ALOAD(p)    __hip_atomic_load((p), __ATOMIC_RELAXED, __HIP_MEMORY_SCOPE_AGENT)
#define ASTORE(p,v) __hip_atomic_store((p), (v), __ATOMIC_RELAXED, __HIP_MEMORY_SCOPE_AGENT)

// ---------------------------------------------------------------------------
// Precompute kernels (unchanged, validated)
// ---------------------------------------------------------------------------
__global__ __launch_bounds__(64) void k_fold(
    const float* __restrict__ W1, const float* __restrict__ Wd,
    const float* __restrict__ bd, const float* __restrict__ b1,
    ushort_t* __restrict__ Wzc, float* __restrict__ bfold)
{
    __shared__ float sW1[2560];
    __shared__ float sWd[INS * DSS];
    __shared__ float red[64];
    const int j = blockIdx.x;
    const int tid = threadIdx.x;
    for (int f = tid; f < INS * DSS; f += 64) sWd[f] = Wd[f];
    for (int f = tid; f < 2560; f += 64) sW1[f] = W1[(size_t)j * CAT + f];
    __syncthreads();
    if (tid < 60) {
        int n = tid / DSS, d = tid - n * DSS;
        float acc = 0.f;
        for (int i = 0; i < INS; ++i) acc += sW1[n * INS + i] * sWd[i * DSS + d];
        Wzc[j * KZ + tid] = f2bf(acc);
    } else {
        Wzc[j * KZ + tid] = 0;
    }
    for (int q = tid; q < HID; q += 64)
        Wzc[j * KZ + 64 + q] = f2bf(W1[(size_t)j * CAT + 2560 + q]);
    float acc = 0.f;
    for (int p = tid; p < 2560; p += 64) acc += sW1[p] * bd[p & (INS - 1)];
    red[tid] = acc;
    __syncthreads();
    for (int s = 32; s > 0; s >>= 1) {
        if (tid < s) red[tid] += red[tid + s];
        __syncthreads();
    }
    if (tid == 0) bfold[j] = b1[j] + red[0];
}

__global__ __launch_bounds__(256) void k_dfold(
    const float* __restrict__ desc, ushort_t* __restrict__ Dfold)
{
    int idx = blockIdx.x * 256 + threadIdx.x;
    int p = idx & 63;
    int tb = idx >> 6;
    int t = tb / BSZ;
    int b = tb - t * BSZ;
    float v = (p < 60) ? desc[(size_t)b * (TT * 60) + t * 60 + p] : 0.f;
    Dfold[idx] = f2bf(v);
}

__global__ __launch_bounds__(256) void k_prep_g(
    const float* __restrict__ Wih, const float* __restrict__ Whh,
    const float* __restrict__ bih, const float* __restrict__ bhh,
    ushort_t* __restrict__ Wg, float* __restrict__ bg)
{
    int idx = blockIdx.x * 256 + threadIdx.x;   // 1024*512
    int newr = idx >> 9, k = idx & 511;
    int j = newr >> 2, g = newr & 3;
    int src_row = g * 256 + j;
    float v = (k < 256) ? Wih[(size_t)src_row * INS + k]
                        : Whh[(size_t)src_row * HID + (k - 256)];
    Wg[idx] = f2bf(v);
    if (k == 0) bg[newr] = bih[src_row] + bhh[src_row];
}

__global__ __launch_bounds__(256) void k_prep_o(
    const float* __restrict__ W2, const float* __restrict__ Wv,
    ushort_t* __restrict__ Wout)
{
    int idx = blockIdx.x * 256 + threadIdx.x;   // 320*2816
    int r = idx / CAT, k = idx - r * CAT;
    float v = 0.f;
    if (r < 256) v = W2[(size_t)r * CAT + k];
    else if (r < NOUT) v = Wv[(size_t)(r - 256) * CAT + k];
    Wout[idx] = f2bf(v);
}

// ---------------------------------------------------------------------------
// Persistent kernel: 256 blocks x 1024 threads. Block = (s = bid&7 K-slice,
// m = bid>>3 -> 16 batch rows). Per step, ONE relaxed grid barrier.
// h, c, z are LDS-resident for the whole kernel (gates computed redundantly
// by the 8 same-m blocks). Cross-block traffic = OF split-K partials only,
// via relaxed agent atomics (sc1, LLC-coherent) -> NO release/acquire, NO
// wbL2/invL2 anywhere (round-4 killer: 256 blocks x full-L2 flush per barrier).
// ---------------------------------------------------------------------------
__global__ void __launch_bounds__(NTHR) k_persist(
    const ushort_t* __restrict__ Wg, const float* __restrict__ bg,
    const ushort_t* __restrict__ Wzc, const float* __restrict__ bfold,
    const ushort_t* __restrict__ Wout, const float* __restrict__ b2,
    const float* __restrict__ bv, const ushort_t* __restrict__ Dfold,
    float* __restrict__ partA, float* __restrict__ partB,
    float* __restrict__ out, unsigned int* __restrict__ bars)
{
    // strides chosen 16B-aligned for ds_read_b128
    __shared__ ushort_t xh[16 * 776];   // [row][0:256 inp | 256:512 h0 | 512:768 h1]
    __shared__ ushort_t dl[16 * 72];    // descriptor slice, row stride 72
    __shared__ ushort_t zt[16 * 360];   // z tile (this block's 352-col K-slice)
    __shared__ float    cl[16 * 257];   // LSTM cell state, full 256 cols
    __shared__ float    sg[16 * 16 * 17]; // per-wave gate staging

    const int bid = blockIdx.x;
    const int tid = threadIdx.x;
    const int w = tid >> 6, l = tid & 63, quad = l >> 4, lr = l & 15;
    const int s = bid & 7, m0 = (bid >> 3) * 16;
    float* sgw = &sg[w * 16 * 17];

    for (int i = tid; i < 16 * 776; i += NTHR) xh[i] = 0;
    for (int i = tid; i < 16 * 257; i += NTHR) cl[i] = 0.f;

    for (int t = 0; t < TT; ++t) {
        const int hc = t & 1, hn = hc ^ 1;
        float*       pw = (t & 1) ? partB : partA;   // this step's partials
        const float* pr = (t & 1) ? partA : partB;   // prev step's partials

        // ---- reduce inp + out[t-1] (sc1 loads, LLC-coherent) + load d ----
        if (t > 0) {
            #pragma unroll
            for (int it = 0; it < 4; ++it) {
                int idx = tid + it * NTHR;
                int row = idx >> 8, col = idx & 255;
                float sum = 0.f;
                #pragma unroll
                for (int s2 = 0; s2 < 8; ++s2)
                    sum += ALOAD(&pr[((size_t)(s2 * 512 + m0 + row)) * 320 + col]);
                xh[row * 776 + col] = f2bf(fmaxf(sum + b2[col], 0.f));
            }
            if (s == 0 && tid < 160) {
                int row = tid / 10, col = tid - row * 10;
                float sum = 0.f;
                #pragma unroll
                for (int s2 = 0; s2 < 8; ++s2)
                    sum += ALOAD(&pr[((size_t)(s2 * 512 + m0 + row)) * 320 + 256 + col]);
                out[(size_t)(m0 + row) * (TT * NDD) + (t - 1) * NDD + col] =
                    sigf(sum + bv[col]);
            }
        }
        if (tid < 128) {
            int row = tid >> 3, q = tid & 7;
            *(sh8*)&dl[row * 72 + q * 8] =
                *(const sh8*)&Dfold[((size_t)t * BSZ + m0 + row) * 64 + q * 8];
        }
        __syncthreads();

        // ---- Phase G: full gates (redundant x8) + cell, all LDS-local ----
        {
            f4 acc[4] = {};
            #pragma unroll
            for (int half = 0; half < 2; ++half) {
                sh8 a[8];
                const int aoff = half ? (256 + hc * 256) : 0;
                #pragma unroll
                for (int ks = 0; ks < 8; ++ks)
                    a[ks] = *(const sh8*)&xh[lr * 776 + aoff + ks * 32 + quad * 8];
                #pragma unroll
                for (int i = 0; i < 4; ++i) {
                    const int nt = w * 4 + i;
                    const ushort_t* bp = Wg + (size_t)(nt * 16 + lr) * 512
                                       + half * 256 + quad * 8;
                    #pragma unroll
                    for (int ks = 0; ks < 8; ++ks)
                        acc[i] = MFMA(a[ks], *(const sh8*)(bp + ks * 32), acc[i]);
                }
            }
            const int b = l & 15, jl = l >> 4;
            #pragma unroll
            for (int i = 0; i < 4; ++i) {
                const int nt = w * 4 + i;
                #pragma unroll
                for (int r = 0; r < 4; ++r)
                    sgw[(quad * 4 + r) * 17 + lr] = acc[i][r];
                // same-wave LDS write->read: ordered, compiler inserts waits
                float ai = sgw[b * 17 + 4 * jl + 0];
                float af = sgw[b * 17 + 4 * jl + 1];
                float ag = sgw[b * 17 + 4 * jl + 2];
                float ao = sgw[b * 17 + 4 * jl + 3];
                f4 bgv = *(const f4*)&bg[nt * 16 + 4 * jl];
                ai += bgv[0]; af += bgv[1]; ag += bgv[2]; ao += bgv[3];
                const int j = nt * 4 + jl;
                float cc = sigf(af) * cl[b * 257 + j] + sigf(ai) * tanhf(ag);
                cl[b * 257 + j] = cc;
                float hh = sigf(ao) * tanhf(cc);
                xh[b * 776 + 256 + hn * 256 + j] = f2bf(hh);
            }
        }
        __syncthreads();

        // ---- Phase Z: z tile (352 cols of this block's K-slice) -> LDS ----
        for (int tl = w; tl < 22; tl += 16) {
            const int n0g = s * 352 + tl * 16;
            f4 acc = {};
            const ushort_t* bp = Wzc + (size_t)(n0g + lr) * KZ + quad * 8;
            #pragma unroll
            for (int ks = 0; ks < 2; ++ks)
                acc = MFMA(*(const sh8*)&dl[lr * 72 + ks * 32 + quad * 8],
                           *(const sh8*)(bp + ks * 32), acc);
            #pragma unroll
            for (int ks = 2; ks < 10; ++ks)
                acc = MFMA(*(const sh8*)&xh[lr * 776 + 256 + hn * 256 + (ks - 2) * 32 + quad * 8],
                           *(const sh8*)(bp + ks * 32), acc);
            const float bia = bfold[n0g + lr];
            #pragma unroll
            for (int r = 0; r < 4; ++r)
                zt[(quad * 4 + r) * 360 + tl * 16 + lr] = f2bf(fmaxf(acc[r] + bia, 0.f));
        }
        __syncthreads();

        // ---- Phase OF: partial = zt @ Wout_slice.T -> sc1 stores ----
        for (int tl = w; tl < 20; tl += 16) {
            const int n0 = tl * 16;
            f4 acc = {};
            const ushort_t* bp = Wout + (size_t)(n0 + lr) * CAT + s * 352 + quad * 8;
            #pragma unroll
            for (int ks = 0; ks < 11; ++ks)
                acc = MFMA(*(const sh8*)&zt[lr * 360 + ks * 32 + quad * 8],
                           *(const sh8*)(bp + ks * 32), acc);
            #pragma unroll
            for (int r = 0; r < 4; ++r)
                ASTORE(&pw[((size_t)(s * 512 + m0 + quad * 4 + r)) * 320 + n0 + lr],
                       acc[r]);
        }

        // ---- ONE relaxed grid barrier (no release/acquire anywhere) ----
        __syncthreads();   // drains vmcnt: all sc1 stores complete
        if (tid == 0) {
            unsigned int* p = bars + t;
            __hip_atomic_fetch_add(p, 1u, __ATOMIC_RELAXED, __HIP_MEMORY_SCOPE_AGENT);
            while (ALOAD(p) < (unsigned int)NBLK)
                __builtin_amdgcn_s_sleep(2);
        }
        __syncthreads();
    }

    // ---- final output row (t = TT-1), partials are in partB (99 & 1) ----
    if (s == 0 && tid < 160) {
        int row = tid / 10, col = tid - row * 10;
        float sum = 0.f;
        #pragma unroll
        for (int s2 = 0; s2 < 8; ++s2)
            sum += ALOAD(&partB[((size_t)(s2 * 512 + m0 + row)) * 320 + 256 + col]);
        out[(size_t)(m0 + row) * (TT * NDD) + (TT - 1) * NDD + col] = sigf(sum + bv[col]);
    }
}

// ---------------------------------------------------------------------------
extern "C" void kernel_launch(void* const* d_in, const int* in_sizes, int n_in,
                              void* d_out, int out_size, void* d_ws, size_t ws_size,
                              hipStream_t stream)
{
    const float* desc = (const float*)d_in[0];
    const float* Wd   = (const float*)d_in[1];
    const float* bd   = (const float*)d_in[2];
    const float* W1   = (const float*)d_in[3];
    const float* b1   = (const float*)d_in[4];
    const float* W2   = (const float*)d_in[5];
    const float* b2   = (const float*)d_in[6];
    const float* Wv   = (const float*)d_in[7];
    const float* bv   = (const float*)d_in[8];
    const float* Wih  = (const float*)d_in[9];
    const float* Whh  = (const float*)d_in[10];
    const float* bih  = (const float*)d_in[11];
    const float* bhh  = (const float*)d_in[12];
    float* out = (float*)d_out;

    char* base = (char*)d_ws;
    size_t off = 0;
    auto alloc = [&](size_t bytes) -> char* {
        char* p = base + off;
        off = (off + bytes + 255) & ~(size_t)255;
        return p;
    };
    ushort_t*     Wzc   = (ushort_t*)alloc((size_t)CAT * KZ * 2);
    float*        bfold = (float*)alloc(CAT * 4);
    ushort_t*     Wg    = (ushort_t*)alloc(1024 * 512 * 2);
    float*        bg    = (float*)alloc(1024 * 4);
    ushort_t*     Wout  = (ushort_t*)alloc((size_t)NOUTP * CAT * 2);
    ushort_t*     Dfold = (ushort_t*)alloc((size_t)TT * BSZ * 64 * 2);
    float*        partA = (float*)alloc((size_t)8 * BSZ * NOUTP * 4);
    float*        partB = (float*)alloc((size_t)8 * BSZ * NOUTP * 4);
    unsigned int* bars  = (unsigned int*)alloc((TT + 4) * 4);

    hipMemsetAsync(bars, 0, (TT + 4) * 4, stream);

    k_fold  <<<CAT, 64, 0, stream>>>(W1, Wd, bd, b1, Wzc, bfold);
    k_dfold <<<(TT * BSZ * 64) / 256, 256, 0, stream>>>(desc, Dfold);
    k_prep_g<<<(1024 * 512) / 256, 256, 0, stream>>>(Wih, Whh, bih, bhh, Wg, bg);
    k_prep_o<<<(NOUTP * CAT) / 256, 256, 0, stream>>>(W2, Wv, Wout);

    void* args[] = {
        (void*)&Wg, (void*)&bg, (void*)&Wzc, (void*)&bfold, (void*)&Wout,
        (void*)&b2, (void*)&bv, (void*)&Dfold, (void*)&partA, (void*)&partB,
        (void*)&out, (void*)&bars
    };
    hipLaunchCooperativeKernel((const void*)k_persist, dim3(NBLK), dim3(NTHR),
                               args, 0, stream);
}

// Round 6
// 3723.928 us; speedup vs baseline: 2.6894x; 2.6894x over previous
//
#include <hip/hip_runtime.h>
#include <math.h>

#define BSZ 512
#define TT  100
#define NDD 10
#define DSS 6
#define INS 256
#define HID 256
#define CAT 2816   // INS*NDD + HID
#define KZ  320
#define NOUTP 320
#define NOUT 266
#define NBLK 256
#define NTHR 1024

typedef short sh8 __attribute__((ext_vector_type(8)));
typedef float f4  __attribute__((ext_vector_type(4)));
typedef unsigned short ushort_t;

__device__ __forceinline__ float sigf(float x) { return 1.0f / (1.0f + expf(-x)); }

__device__ __forceinline__ ushort_t f2bf(float f) {
    union { float f; unsigned int u; } v; v.f = f;
    unsigned int r = (v.u + 0x7FFFu + ((v.u >> 16) & 1u)) >> 16;
    return (ushort_t)r;
}

#define MFMA(a, b, c) __builtin_amdgcn_mfma_f32_16x16x32_bf16((a), (b), (c), 0, 0, 0)
#define ALOAD(p)    __hip_atomic_load((p), __ATOMIC_RELAXED, __HIP_MEMORY_SCOPE_AGENT)
#define ASTORE(p,v) __hip_atomic_store((p), (v), __ATOMIC_RELAXED, __HIP_MEMORY_SCOPE_AGENT)

// ---------------------------------------------------------------------------
// Precompute kernels (unchanged, validated)
// ---------------------------------------------------------------------------
__global__ __launch_bounds__(64) void k_fold(
    const float* __restrict__ W1, const float* __restrict__ Wd,
    const float* __restrict__ bd, const float* __restrict__ b1,
    ushort_t* __restrict__ Wzc, float* __restrict__ bfold)
{
    __shared__ float sW1[2560];
    __shared__ float sWd[INS * DSS];
    __shared__ float red[64];
    const int j = blockIdx.x;
    const int tid = threadIdx.x;
    for (int f = tid; f < INS * DSS; f += 64) sWd[f] = Wd[f];
    for (int f = tid; f < 2560; f += 64) sW1[f] = W1[(size_t)j * CAT + f];
    __syncthreads();
    if (tid < 60) {
        int n = tid / DSS, d = tid - n * DSS;
        float acc = 0.f;
        for (int i = 0; i < INS; ++i) acc += sW1[n * INS + i] * sWd[i * DSS + d];
        Wzc[j * KZ + tid] = f2bf(acc);
    } else {
        Wzc[j * KZ + tid] = 0;
    }
    for (int q = tid; q < HID; q += 64)
        Wzc[j * KZ + 64 + q] = f2bf(W1[(size_t)j * CAT + 2560 + q]);
    float acc = 0.f;
    for (int p = tid; p < 2560; p += 64) acc += sW1[p] * bd[p & (INS - 1)];
    red[tid] = acc;
    __syncthreads();
    for (int s = 32; s > 0; s >>= 1) {
        if (tid < s) red[tid] += red[tid + s];
        __syncthreads();
    }
    if (tid == 0) bfold[j] = b1[j] + red[0];
}

__global__ __launch_bounds__(256) void k_dfold(
    const float* __restrict__ desc, ushort_t* __restrict__ Dfold)
{
    int idx = blockIdx.x * 256 + threadIdx.x;
    int p = idx & 63;
    int tb = idx >> 6;
    int t = tb / BSZ;
    int b = tb - t * BSZ;
    float v = (p < 60) ? desc[(size_t)b * (TT * 60) + t * 60 + p] : 0.f;
    Dfold[idx] = f2bf(v);
}

__global__ __launch_bounds__(256) void k_prep_g(
    const float* __restrict__ Wih, const float* __restrict__ Whh,
    const float* __restrict__ bih, const float* __restrict__ bhh,
    ushort_t* __restrict__ Wg, float* __restrict__ bg)
{
    int idx = blockIdx.x * 256 + threadIdx.x;   // 1024*512
    int newr = idx >> 9, k = idx & 511;
    int j = newr >> 2, g = newr & 3;
    int src_row = g * 256 + j;
    float v = (k < 256) ? Wih[(size_t)src_row * INS + k]
                        : Whh[(size_t)src_row * HID + (k - 256)];
    Wg[idx] = f2bf(v);
    if (k == 0) bg[newr] = bih[src_row] + bhh[src_row];
}

__global__ __launch_bounds__(256) void k_prep_o(
    const float* __restrict__ W2, const float* __restrict__ Wv,
    ushort_t* __restrict__ Wout)
{
    int idx = blockIdx.x * 256 + threadIdx.x;   // 320*2816
    int r = idx / CAT, k = idx - r * CAT;
    float v = 0.f;
    if (r < 256) v = W2[(size_t)r * CAT + k];
    else if (r < NOUT) v = Wv[(size_t)(r - 256) * CAT + k];
    Wout[idx] = f2bf(v);
}

// ---------------------------------------------------------------------------
// Flat relaxed grid barrier (proven protocol: no release/acquire anywhere).
// ---------------------------------------------------------------------------
__device__ __forceinline__ void gridbar(unsigned int* bars, int idx) {
    __syncthreads();   // all waves' global stores drained (vmcnt) before arrive
    if (threadIdx.x == 0) {
        unsigned int* p = bars + idx;
        __hip_atomic_fetch_add(p, 1u, __ATOMIC_RELAXED, __HIP_MEMORY_SCOPE_AGENT);
        while (ALOAD(p) < (unsigned int)NBLK)
            __builtin_amdgcn_s_sleep(2);
    }
    __syncthreads();
}

// ---------------------------------------------------------------------------
// Persistent kernel, non-redundant partition. Block = (s = bid&7, m = bid>>3
// -> 16 batch rows). 3 relaxed barriers/step.
//   A: reduce prev-step OF partials (col slice s*40..+40, 1x coverage) ->
//      inp (sc1) ; s==6 also emits out[t-1] sigmoid.
//   B: gates N-slice s*128..+128 (Wg slice 128 KB, L2-resident per XCD) +
//      cell for h cols s*32..+32 (c in LDS) -> h (sc1).
//   C: z cols s*352..+352 (LDS) -> OF partials K-slice s (sc1).
// Weights per XCD ~0.6 MB (L2-resident); sc1 traffic ~17 MB/step device-wide
// (round 5: 173 MB/step fetch from redundant Wg + redundant reduce).
// ---------------------------------------------------------------------------
__global__ void __launch_bounds__(NTHR) k_persist(
    const ushort_t* __restrict__ Wg, const float* __restrict__ bg,
    const ushort_t* __restrict__ Wzc, const float* __restrict__ bfold,
    const ushort_t* __restrict__ Wout, const float* __restrict__ b2,
    const float* __restrict__ bv, const ushort_t* __restrict__ Dfold,
    ushort_t* __restrict__ xh,          // [512][768]: inp | h(even) | h(odd)
    float* __restrict__ partA, float* __restrict__ partB,
    float* __restrict__ out, unsigned int* __restrict__ bars)
{
    __shared__ ushort_t sxh[16 * 520];   // B: [inp|h_prev], K=512, stride 520
    __shared__ ushort_t sa[16 * 328];    // C: [d|h_cur],   K=320, stride 328
    __shared__ ushort_t zt[16 * 360];    // C: z tile 16x352, stride 360
    __shared__ float    sg[16 * 132];    // B: gate staging 16 rows x 128
    __shared__ float    cl[16 * 33];     // cell state, 16 rows x 32 owned cols

    const int bid = blockIdx.x;
    const int tid = threadIdx.x;
    const int w = tid >> 6, l = tid & 63, quad = l >> 4, lr = l & 15;
    const int s = bid & 7, m0 = (bid >> 3) * 16;
    unsigned int* xh_u  = (unsigned int*)xh;    // row stride 384 uints
    unsigned int* sxh_u = (unsigned int*)sxh;
    unsigned int* sa_u  = (unsigned int*)sa;

    // init: zero own xh rows (8x same-value redundancy, benign) + own c slice
    for (int i = tid; i < 16 * 33; i += NTHR) cl[i] = 0.f;
    for (int i = tid; i < 16 * 384; i += NTHR) {
        int row = i / 384, q = i - row * 384;
        ASTORE(&xh_u[(size_t)(m0 + row) * 384 + q], 0u);
    }
    gridbar(bars, 300);

    for (int t = 0; t < TT; ++t) {
        const int hcur  = 256 + (t & 1) * 256;        // ushort col offset of h_t
        const int hprev = 256 + ((t + 1) & 1) * 256;  // ushort col offset of h_{t-1}
        float*       pw = (t & 1) ? partB : partA;
        const float* pr = (t & 1) ? partA : partB;

        // ================= Phase A: reduce partials -> inp, out[t-1] ======
        if (t > 0) {
            const int cs = s * 40;
            if (tid < 320) {
                int row = tid / 20, cp = tid % 20;
                int c0 = cs + cp * 2;
                float s0 = 0.f, s1 = 0.f;
                #pragma unroll
                for (int s2 = 0; s2 < 8; ++s2) {
                    const float* pb = &pr[((size_t)(s2 * 512 + m0 + row)) * 320 + c0];
                    s0 += ALOAD(&pb[0]);
                    s1 += ALOAD(&pb[1]);
                }
                if (c0 + 1 < 256) {
                    unsigned int v = (unsigned int)f2bf(fmaxf(s0 + b2[c0], 0.f))
                        | ((unsigned int)f2bf(fmaxf(s1 + b2[c0 + 1], 0.f)) << 16);
                    ASTORE(&xh_u[(size_t)(m0 + row) * 384 + (c0 >> 1)], v);
                }
            } else if (s == 6 && tid >= 512 && tid < 672) {
                int k = tid - 512, row = k / 10, col = k - row * 10;
                float sum = 0.f;
                #pragma unroll
                for (int s2 = 0; s2 < 8; ++s2)
                    sum += ALOAD(&pr[((size_t)(s2 * 512 + m0 + row)) * 320 + 256 + col]);
                out[(size_t)(m0 + row) * (TT * NDD) + (t - 1) * NDD + col] =
                    sigf(sum + bv[col]);
            }
            gridbar(bars, 3 * t);
        }

        // ================= Phase B: gates slice + cell ====================
        #pragma unroll
        for (int it = 0; it < 4; ++it) {
            int idx = tid + it * NTHR;
            int row = idx >> 8, q = idx & 255;
            unsigned int v = (q < 128)
                ? ALOAD(&xh_u[(size_t)(m0 + row) * 384 + q])
                : ALOAD(&xh_u[(size_t)(m0 + row) * 384 + (hprev >> 1) + (q - 128)]);
            sxh_u[row * 260 + q] = v;
        }
        __syncthreads();
        {
            const int tile = w & 7, kh = w >> 3;
            f4 acc = {};
            const ushort_t* bp = Wg + (size_t)(s * 128 + tile * 16 + lr) * 512
                               + kh * 256 + quad * 8;
            const ushort_t* ap = &sxh[lr * 520 + kh * 256 + quad * 8];
            #pragma unroll
            for (int ks = 0; ks < 8; ++ks)
                acc = MFMA(*(const sh8*)(ap + ks * 32), *(const sh8*)(bp + ks * 32), acc);
            if (kh == 0) {
                #pragma unroll
                for (int r = 0; r < 4; ++r)
                    sg[(quad * 4 + r) * 132 + tile * 16 + lr] = acc[r];
            }
            __syncthreads();
            if (kh == 1) {
                #pragma unroll
                for (int r = 0; r < 4; ++r)
                    sg[(quad * 4 + r) * 132 + tile * 16 + lr] += acc[r];
            }
            __syncthreads();
            if (tid < 256) {
                int row = tid >> 4, jp = tid & 15;
                float g8[8];
                #pragma unroll
                for (int i = 0; i < 8; ++i)
                    g8[i] = sg[row * 132 + jp * 8 + i] + bg[s * 128 + jp * 8 + i];
                unsigned int pair = 0;
                #pragma unroll
                for (int h2 = 0; h2 < 2; ++h2) {
                    float ai = g8[h2 * 4 + 0], af = g8[h2 * 4 + 1];
                    float ag = g8[h2 * 4 + 2], ao = g8[h2 * 4 + 3];
                    int jc = jp * 2 + h2;            // local h col 0..31
                    float cc = sigf(af) * cl[row * 33 + jc] + sigf(ai) * tanhf(ag);
                    cl[row * 33 + jc] = cc;
                    float hh = sigf(ao) * tanhf(cc);
                    pair |= ((unsigned int)f2bf(hh)) << (16 * h2);
                }
                ASTORE(&xh_u[(size_t)(m0 + row) * 384 + (hcur >> 1) + s * 16 + jp], pair);
            }
        }
        gridbar(bars, 3 * t + 1);

        // ================= Phase C: z slice + OF partials =================
        if (tid < 512) {
            int row = tid >> 5, q = tid & 31;
            sa_u[row * 164 + q] =
                *(const unsigned int*)&Dfold[((size_t)t * BSZ + m0 + row) * 64 + q * 2];
        }
        #pragma unroll
        for (int it = 0; it < 2; ++it) {
            int idx = tid + it * NTHR;
            int row = idx >> 7, q = idx & 127;
            sa_u[row * 164 + 32 + q] =
                ALOAD(&xh_u[(size_t)(m0 + row) * 384 + (hcur >> 1) + q]);
        }
        __syncthreads();
        for (int tl = w; tl < 22; tl += 16) {
            int n0g = s * 352 + tl * 16;
            f4 acc = {};
            const ushort_t* bp = Wzc + (size_t)(n0g + lr) * KZ + quad * 8;
            const ushort_t* ap = &sa[lr * 328 + quad * 8];
            #pragma unroll
            for (int ks = 0; ks < 10; ++ks)
                acc = MFMA(*(const sh8*)(ap + ks * 32), *(const sh8*)(bp + ks * 32), acc);
            float bia = bfold[n0g + lr];
            #pragma unroll
            for (int r = 0; r < 4; ++r)
                zt[(quad * 4 + r) * 360 + tl * 16 + lr] = f2bf(fmaxf(acc[r] + bia, 0.f));
        }
        __syncthreads();
        for (int tl = w; tl < 20; tl += 16) {
            int n0 = tl * 16;
            f4 acc = {};
            const ushort_t* bp = Wout + (size_t)(n0 + lr) * CAT + s * 352 + quad * 8;
            const ushort_t* ap = &zt[lr * 360 + quad * 8];
            #pragma unroll
            for (int ks = 0; ks < 11; ++ks)
                acc = MFMA(*(const sh8*)(ap + ks * 32), *(const sh8*)(bp + ks * 32), acc);
            #pragma unroll
            for (int r = 0; r < 4; ++r)
                ASTORE(&pw[((size_t)(s * 512 + m0 + quad * 4 + r)) * 320 + n0 + lr],
                       acc[r]);
        }
        gridbar(bars, 3 * t + 2);
    }

    // final out row (t = TT-1): partials in partB (99 odd)
    if (s == 6 && tid < 160) {
        int row = tid / 10, col = tid - row * 10;
        float sum = 0.f;
        #pragma unroll
        for (int s2 = 0; s2 < 8; ++s2)
            sum += ALOAD(&partB[((size_t)(s2 * 512 + m0 + row)) * 320 + 256 + col]);
        out[(size_t)(m0 + row) * (TT * NDD) + (TT - 1) * NDD + col] = sigf(sum + bv[col]);
    }
}

// ---------------------------------------------------------------------------
extern "C" void kernel_launch(void* const* d_in, const int* in_sizes, int n_in,
                              void* d_out, int out_size, void* d_ws, size_t ws_size,
                              hipStream_t stream)
{
    const float* desc = (const float*)d_in[0];
    const float* Wd   = (const float*)d_in[1];
    const float* bd   = (const float*)d_in[2];
    const float* W1   = (const float*)d_in[3];
    const float* b1   = (const float*)d_in[4];
    const float* W2   = (const float*)d_in[5];
    const float* b2   = (const float*)d_in[6];
    const float* Wv   = (const float*)d_in[7];
    const float* bv   = (const float*)d_in[8];
    const float* Wih  = (const float*)d_in[9];
    const float* Whh  = (const float*)d_in[10];
    const float* bih  = (const float*)d_in[11];
    const float* bhh  = (const float*)d_in[12];
    float* out = (float*)d_out;

    char* base = (char*)d_ws;
    size_t off = 0;
    auto alloc = [&](size_t bytes) -> char* {
        char* p = base + off;
        off = (off + bytes + 255) & ~(size_t)255;
        return p;
    };
    ushort_t*     Wzc   = (ushort_t*)alloc((size_t)CAT * KZ * 2);
    float*        bfold = (float*)alloc(CAT * 4);
    ushort_t*     Wg    = (ushort_t*)alloc(1024 * 512 * 2);
    float*        bg    = (float*)alloc(1024 * 4);
    ushort_t*     Wout  = (ushort_t*)alloc((size_t)NOUTP * CAT * 2);
    ushort_t*     Dfold = (ushort_t*)alloc((size_t)TT * BSZ * 64 * 2);
    ushort_t*     xh    = (ushort_t*)alloc((size_t)BSZ * 768 * 2);
    float*        partA = (float*)alloc((size_t)8 * BSZ * NOUTP * 4);
    float*        partB = (float*)alloc((size_t)8 * BSZ * NOUTP * 4);
    unsigned int* bars  = (unsigned int*)alloc((TT * 3 + 8) * 4);

    hipMemsetAsync(bars, 0, (TT * 3 + 8) * 4, stream);

    k_fold  <<<CAT, 64, 0, stream>>>(W1, Wd, bd, b1, Wzc, bfold);
    k_dfold <<<(TT * BSZ * 64) / 256, 256, 0, stream>>>(desc, Dfold);
    k_prep_g<<<(1024 * 512) / 256, 256, 0, stream>>>(Wih, Whh, bih, bhh, Wg, bg);
    k_prep_o<<<(NOUTP * CAT) / 256, 256, 0, stream>>>(W2, Wv, Wout);

    void* args[] = {
        (void*)&Wg, (void*)&bg, (void*)&Wzc, (void*)&bfold, (void*)&Wout,
        (void*)&b2, (void*)&bv, (void*)&Dfold, (void*)&xh,
        (void*)&partA, (void*)&partB, (void*)&out, (void*)&bars
    };
    hipLaunchCooperativeKernel((const void*)k_persist, dim3(NBLK), dim3(NTHR),
                               args, 0, stream);
}

// Round 8
// 2346.482 us; speedup vs baseline: 4.2681x; 1.5870x over previous
//
#include <hip/hip_runtime.h>
#include <math.h>

#define BSZ 512
#define TT  100
#define NDD 10
#define DSS 6
#define INS 256
#define HID 256
#define CAT 2816   // INS*NDD + HID
#define KZ  320
#define NOUTP 320
#define NOUT 266
#define NBLK 256
#define NTHR 1024

typedef short sh8 __attribute__((ext_vector_type(8)));
typedef float f4  __attribute__((ext_vector_type(4)));
typedef unsigned int u4 __attribute__((ext_vector_type(4)));
typedef unsigned short ushort_t;

__device__ __forceinline__ float sigf(float x) { return 1.0f / (1.0f + expf(-x)); }

__device__ __forceinline__ ushort_t f2bf(float f) {
    union { float f; unsigned int u; } v; v.f = f;
    unsigned int r = (v.u + 0x7FFFu + ((v.u >> 16) & 1u)) >> 16;
    return (ushort_t)r;
}

#define MFMA(a, b, c) __builtin_amdgcn_mfma_f32_16x16x32_bf16((a), (b), (c), 0, 0, 0)
#define ALOAD(p)    __hip_atomic_load((p), __ATOMIC_RELAXED, __HIP_MEMORY_SCOPE_AGENT)
#define ASTORE(p,v) __hip_atomic_store((p), (v), __ATOMIC_RELAXED, __HIP_MEMORY_SCOPE_AGENT)

// 16B L1+L2-bypassing load (agent-coherent, matches sc1 store visibility).
// "=&v" earlyclobber is MANDATORY: global_load writes dest asynchronously,
// so dest must never overlap another pending load's address pair (round-7
// crash: non-earlyclobber outputs overlapped input address VGPRs).
__device__ __forceinline__ u4 aload16(const unsigned int* p) {
    u4 r;
    asm volatile("global_load_dwordx4 %0, %1, off sc0 sc1\n\ts_waitcnt vmcnt(0)"
                 : "=&v"(r) : "v"(p) : "memory");
    return r;
}
// 4 x 16B batched: issue all, one wait
__device__ __forceinline__ void aload16x4(f4* a, const float* p0, const float* p1,
                                          const float* p2, const float* p3) {
    asm volatile(
        "global_load_dwordx4 %0, %4, off sc0 sc1\n\t"
        "global_load_dwordx4 %1, %5, off sc0 sc1\n\t"
        "global_load_dwordx4 %2, %6, off sc0 sc1\n\t"
        "global_load_dwordx4 %3, %7, off sc0 sc1\n\t"
        "s_waitcnt vmcnt(0)"
        : "=&v"(a[0]), "=&v"(a[1]), "=&v"(a[2]), "=&v"(a[3])
        : "v"(p0), "v"(p1), "v"(p2), "v"(p3)
        : "memory");
}

// ---------------------------------------------------------------------------
// Precompute kernels (unchanged, validated)
// ---------------------------------------------------------------------------
__global__ __launch_bounds__(64) void k_fold(
    const float* __restrict__ W1, const float* __restrict__ Wd,
    const float* __restrict__ bd, const float* __restrict__ b1,
    ushort_t* __restrict__ Wzc, float* __restrict__ bfold)
{
    __shared__ float sW1[2560];
    __shared__ float sWd[INS * DSS];
    __shared__ float red[64];
    const int j = blockIdx.x;
    const int tid = threadIdx.x;
    for (int f = tid; f < INS * DSS; f += 64) sWd[f] = Wd[f];
    for (int f = tid; f < 2560; f += 64) sW1[f] = W1[(size_t)j * CAT + f];
    __syncthreads();
    if (tid < 60) {
        int n = tid / DSS, d = tid - n * DSS;
        float acc = 0.f;
        for (int i = 0; i < INS; ++i) acc += sW1[n * INS + i] * sWd[i * DSS + d];
        Wzc[j * KZ + tid] = f2bf(acc);
    } else {
        Wzc[j * KZ + tid] = 0;
    }
    for (int q = tid; q < HID; q += 64)
        Wzc[j * KZ + 64 + q] = f2bf(W1[(size_t)j * CAT + 2560 + q]);
    float acc = 0.f;
    for (int p = tid; p < 2560; p += 64) acc += sW1[p] * bd[p & (INS - 1)];
    red[tid] = acc;
    __syncthreads();
    for (int s = 32; s > 0; s >>= 1) {
        if (tid < s) red[tid] += red[tid + s];
        __syncthreads();
    }
    if (tid == 0) bfold[j] = b1[j] + red[0];
}

__global__ __launch_bounds__(256) void k_dfold(
    const float* __restrict__ desc, ushort_t* __restrict__ Dfold)
{
    int idx = blockIdx.x * 256 + threadIdx.x;
    int p = idx & 63;
    int tb = idx >> 6;
    int t = tb / BSZ;
    int b = tb - t * BSZ;
    float v = (p < 60) ? desc[(size_t)b * (TT * 60) + t * 60 + p] : 0.f;
    Dfold[idx] = f2bf(v);
}

__global__ __launch_bounds__(256) void k_prep_g(
    const float* __restrict__ Wih, const float* __restrict__ Whh,
    const float* __restrict__ bih, const float* __restrict__ bhh,
    ushort_t* __restrict__ Wg, float* __restrict__ bg)
{
    int idx = blockIdx.x * 256 + threadIdx.x;   // 1024*512
    int newr = idx >> 9, k = idx & 511;
    int j = newr >> 2, g = newr & 3;
    int src_row = g * 256 + j;
    float v = (k < 256) ? Wih[(size_t)src_row * INS + k]
                        : Whh[(size_t)src_row * HID + (k - 256)];
    Wg[idx] = f2bf(v);
    if (k == 0) bg[newr] = bih[src_row] + bhh[src_row];
}

__global__ __launch_bounds__(256) void k_prep_o(
    const float* __restrict__ W2, const float* __restrict__ Wv,
    ushort_t* __restrict__ Wout)
{
    int idx = blockIdx.x * 256 + threadIdx.x;   // 320*2816
    int r = idx / CAT, k = idx - r * CAT;
    float v = 0.f;
    if (r < 256) v = W2[(size_t)r * CAT + k];
    else if (r < NOUT) v = Wv[(size_t)(r - 256) * CAT + k];
    Wout[idx] = f2bf(v);
}

// ---------------------------------------------------------------------------
// GROUP barrier: only the 8 blocks of one m-group (rows m0..m0+15) sync.
// Round-6 cost: 3 global barriers x 256-way RMW on one line. Groups are
// fully independent (batch rows never interact across groups).
// ---------------------------------------------------------------------------
__device__ __forceinline__ void gbar(unsigned int* gb, int idx) {
    __syncthreads();   // drains vmcnt: block's sc1 stores complete
    if (threadIdx.x == 0) {
        unsigned int* p = gb + idx;
        __hip_atomic_fetch_add(p, 1u, __ATOMIC_RELAXED, __HIP_MEMORY_SCOPE_AGENT);
        while (ALOAD(p) < 8u)
            __builtin_amdgcn_s_sleep(1);
    }
    __syncthreads();
}

// ---------------------------------------------------------------------------
// Persistent kernel. Block = (s = bid&7 slice, grp = bid>>3 -> 16 batch rows).
// 3 per-group barriers/step; sc1 staging reads widened to dwordx4.
// ---------------------------------------------------------------------------
__global__ void __launch_bounds__(NTHR) k_persist(
    const ushort_t* __restrict__ Wg, const float* __restrict__ bg,
    const ushort_t* __restrict__ Wzc, const float* __restrict__ bfold,
    const ushort_t* __restrict__ Wout, const float* __restrict__ b2,
    const float* __restrict__ bv, const ushort_t* __restrict__ Dfold,
    ushort_t* __restrict__ xh,          // [512][768]: inp | h(even) | h(odd)
    float* __restrict__ partA, float* __restrict__ partB,
    float* __restrict__ out, unsigned int* __restrict__ bars)
{
    __shared__ ushort_t sxh[16 * 520];   // B: [inp|h_prev], K=512, stride 520
    __shared__ ushort_t sa[16 * 328];    // C: [d|h_cur],   K=320, stride 328
    __shared__ ushort_t zt[16 * 360];    // C: z tile 16x352, stride 360
    __shared__ float    sg[16 * 132];    // B: gate staging
    __shared__ float    cl[16 * 33];     // cell state slice

    const int bid = blockIdx.x;
    const int tid = threadIdx.x;
    const int w = tid >> 6, l = tid & 63, quad = l >> 4, lr = l & 15;
    const int s = bid & 7, grp = bid >> 3, m0 = grp * 16;
    unsigned int* xh_u  = (unsigned int*)xh;    // row stride 384 uints
    unsigned int* sxh_u = (unsigned int*)sxh;
    unsigned int* sa_u  = (unsigned int*)sa;
    unsigned int* gb = bars + grp * 320;

    // init: zero own col-slice of group's 16 xh rows + own c slice
    for (int i = tid; i < 16 * 33; i += NTHR) cl[i] = 0.f;
    if (tid < 192) {
        int row = tid / 12, v = tid % 12;
        int q = s * 48 + v * 4;
        #pragma unroll
        for (int k = 0; k < 4; ++k)
            ASTORE(&xh_u[(size_t)(m0 + row) * 384 + q + k], 0u);
    }
    gbar(gb, 300);

    for (int t = 0; t < TT; ++t) {
        const int hcur  = 256 + (t & 1) * 256;
        const int hprev = 256 + ((t + 1) & 1) * 256;
        float*       pw = (t & 1) ? partB : partA;
        const float* pr = (t & 1) ? partA : partB;

        // ============ Phase A: reduce partials -> inp, out[t-1] ============
        if (t > 0) {
            int row = -1, chunk = 0;
            if (s < 6 && tid < 160)      { row = tid / 10; chunk = tid % 10; }
            else if (s == 6 && tid < 64) { row = tid >> 2; chunk = tid & 3; }
            if (row >= 0) {
                const int c0 = s * 40 + chunk * 4;
                f4 a[4], b[4];
                const float* base = &pr[((size_t)(m0 + row)) * 320 + c0];
                aload16x4(a, base + (size_t)0 * 512 * 320, base + (size_t)1 * 512 * 320,
                             base + (size_t)2 * 512 * 320, base + (size_t)3 * 512 * 320);
                aload16x4(b, base + (size_t)4 * 512 * 320, base + (size_t)5 * 512 * 320,
                             base + (size_t)6 * 512 * 320, base + (size_t)7 * 512 * 320);
                f4 sum = a[0] + a[1] + a[2] + a[3] + b[0] + b[1] + b[2] + b[3];
                f4 bb = *(const f4*)&b2[c0];
                unsigned int v0 = (unsigned int)f2bf(fmaxf(sum[0] + bb[0], 0.f))
                    | ((unsigned int)f2bf(fmaxf(sum[1] + bb[1], 0.f)) << 16);
                unsigned int v1 = (unsigned int)f2bf(fmaxf(sum[2] + bb[2], 0.f))
                    | ((unsigned int)f2bf(fmaxf(sum[3] + bb[3], 0.f)) << 16);
                ASTORE(&xh_u[(size_t)(m0 + row) * 384 + (c0 >> 1)], v0);
                ASTORE(&xh_u[(size_t)(m0 + row) * 384 + (c0 >> 1) + 1], v1);
            }
            if (s == 6 && tid >= 512 && tid < 672) {
                int k = tid - 512, r2 = k / 10, col = k - r2 * 10;
                float sum = 0.f;
                #pragma unroll
                for (int s2 = 0; s2 < 8; ++s2)
                    sum += ALOAD(&pr[((size_t)(s2 * 512 + m0 + r2)) * 320 + 256 + col]);
                out[(size_t)(m0 + r2) * (TT * NDD) + (t - 1) * NDD + col] =
                    sigf(sum + bv[col]);
            }
            gbar(gb, 3 * t);
        }

        // ============ Phase B: gates slice + cell ==========================
        {
            int row = tid >> 6, q4 = tid & 63;
            const unsigned int* src = (q4 < 32)
                ? &xh_u[(size_t)(m0 + row) * 384 + q4 * 4]
                : &xh_u[(size_t)(m0 + row) * 384 + (hprev >> 1) + (q4 - 32) * 4];
            *(u4*)&sxh_u[row * 260 + q4 * 4] = aload16(src);
        }
        __syncthreads();
        {
            const int tile = w & 7, kh = w >> 3;
            f4 acc = {};
            const ushort_t* bp = Wg + (size_t)(s * 128 + tile * 16 + lr) * 512
                               + kh * 256 + quad * 8;
            const ushort_t* ap = &sxh[lr * 520 + kh * 256 + quad * 8];
            #pragma unroll
            for (int ks = 0; ks < 8; ++ks)
                acc = MFMA(*(const sh8*)(ap + ks * 32), *(const sh8*)(bp + ks * 32), acc);
            if (kh == 0) {
                #pragma unroll
                for (int r = 0; r < 4; ++r)
                    sg[(quad * 4 + r) * 132 + tile * 16 + lr] = acc[r];
            }
            __syncthreads();
            if (kh == 1) {
                #pragma unroll
                for (int r = 0; r < 4; ++r)
                    sg[(quad * 4 + r) * 132 + tile * 16 + lr] += acc[r];
            }
            __syncthreads();
            if (tid < 256) {
                int row = tid >> 4, jp = tid & 15;
                float g8[8];
                #pragma unroll
                for (int i = 0; i < 8; ++i)
                    g8[i] = sg[row * 132 + jp * 8 + i] + bg[s * 128 + jp * 8 + i];
                unsigned int pair = 0;
                #pragma unroll
                for (int h2 = 0; h2 < 2; ++h2) {
                    float ai = g8[h2 * 4 + 0], af = g8[h2 * 4 + 1];
                    float ag = g8[h2 * 4 + 2], ao = g8[h2 * 4 + 3];
                    int jc = jp * 2 + h2;
                    float cc = sigf(af) * cl[row * 33 + jc] + sigf(ai) * tanhf(ag);
                    cl[row * 33 + jc] = cc;
                    float hh = sigf(ao) * tanhf(cc);
                    pair |= ((unsigned int)f2bf(hh)) << (16 * h2);
                }
                ASTORE(&xh_u[(size_t)(m0 + row) * 384 + (hcur >> 1) + s * 16 + jp], pair);
            }
        }
        gbar(gb, 3 * t + 1);

        // ============ Phase C: z slice + OF partials =======================
        if (tid < 128) {
            int row = tid >> 3, v = tid & 7;
            *(u4*)&sa_u[row * 164 + v * 4] =
                *(const u4*)&Dfold[((size_t)t * BSZ + m0 + row) * 64 + v * 8];
        } else if (tid >= 256 && tid < 768) {
            int k = tid - 256;
            int row = k >> 5, v = k & 31;
            *(u4*)&sa_u[row * 164 + 32 + v * 4] =
                aload16(&xh_u[(size_t)(m0 + row) * 384 + (hcur >> 1) + v * 4]);
        }
        __syncthreads();
        for (int tl = w; tl < 22; tl += 16) {
            int n0g = s * 352 + tl * 16;
            f4 acc = {};
            const ushort_t* bp = Wzc + (size_t)(n0g + lr) * KZ + quad * 8;
            const ushort_t* ap = &sa[lr * 328 + quad * 8];
            #pragma unroll
            for (int ks = 0; ks < 10; ++ks)
                acc = MFMA(*(const sh8*)(ap + ks * 32), *(const sh8*)(bp + ks * 32), acc);
            float bia = bfold[n0g + lr];
            #pragma unroll
            for (int r = 0; r < 4; ++r)
                zt[(quad * 4 + r) * 360 + tl * 16 + lr] = f2bf(fmaxf(acc[r] + bia, 0.f));
        }
        __syncthreads();
        for (int tl = w; tl < 20; tl += 16) {
            int n0 = tl * 16;
            f4 acc = {};
            const ushort_t* bp = Wout + (size_t)(n0 + lr) * CAT + s * 352 + quad * 8;
            const ushort_t* ap = &zt[lr * 360 + quad * 8];
            #pragma unroll
            for (int ks = 0; ks < 11; ++ks)
                acc = MFMA(*(const sh8*)(ap + ks * 32), *(const sh8*)(bp + ks * 32), acc);
            #pragma unroll
            for (int r = 0; r < 4; ++r)
                ASTORE(&pw[((size_t)(s * 512 + m0 + quad * 4 + r)) * 320 + n0 + lr],
                       acc[r]);
        }
        gbar(gb, 3 * t + 2);
    }

    // final out row (t = TT-1): partials in partB
    if (s == 6 && tid < 160) {
        int row = tid / 10, col = tid - row * 10;
        float sum = 0.f;
        #pragma unroll
        for (int s2 = 0; s2 < 8; ++s2)
            sum += ALOAD(&partB[((size_t)(s2 * 512 + m0 + row)) * 320 + 256 + col]);
        out[(size_t)(m0 + row) * (TT * NDD) + (TT - 1) * NDD + col] = sigf(sum + bv[col]);
    }
}

// ---------------------------------------------------------------------------
extern "C" void kernel_launch(void* const* d_in, const int* in_sizes, int n_in,
                              void* d_out, int out_size, void* d_ws, size_t ws_size,
                              hipStream_t stream)
{
    const float* desc = (const float*)d_in[0];
    const float* Wd   = (const float*)d_in[1];
    const float* bd   = (const float*)d_in[2];
    const float* W1   = (const float*)d_in[3];
    const float* b1   = (const float*)d_in[4];
    const float* W2   = (const float*)d_in[5];
    const float* b2   = (const float*)d_in[6];
    const float* Wv   = (const float*)d_in[7];
    const float* bv   = (const float*)d_in[8];
    const float* Wih  = (const float*)d_in[9];
    const float* Whh  = (const float*)d_in[10];
    const float* bih  = (const float*)d_in[11];
    const float* bhh  = (const float*)d_in[12];
    float* out = (float*)d_out;

    char* base = (char*)d_ws;
    size_t off = 0;
    auto alloc = [&](size_t bytes) -> char* {
        char* p = base + off;
        off = (off + bytes + 255) & ~(size_t)255;
        return p;
    };
    ushort_t*     Wzc   = (ushort_t*)alloc((size_t)CAT * KZ * 2);
    float*        bfold = (float*)alloc(CAT * 4);
    ushort_t*     Wg    = (ushort_t*)alloc(1024 * 512 * 2);
    float*        bg    = (float*)alloc(1024 * 4);
    ushort_t*     Wout  = (ushort_t*)alloc((size_t)NOUTP * CAT * 2);
    ushort_t*     Dfold = (ushort_t*)alloc((size_t)TT * BSZ * 64 * 2);
    ushort_t*     xh    = (ushort_t*)alloc((size_t)BSZ * 768 * 2);
    float*        partA = (float*)alloc((size_t)8 * BSZ * NOUTP * 4);
    float*        partB = (float*)alloc((size_t)8 * BSZ * NOUTP * 4);
    unsigned int* bars  = (unsigned int*)alloc(32 * 320 * 4);

    hipMemsetAsync(bars, 0, 32 * 320 * 4, stream);

    k_fold  <<<CAT, 64, 0, stream>>>(W1, Wd, bd, b1, Wzc, bfold);
    k_dfold <<<(TT * BSZ * 64) / 256, 256, 0, stream>>>(desc, Dfold);
    k_prep_g<<<(1024 * 512) / 256, 256, 0, stream>>>(Wih, Whh, bih, bhh, Wg, bg);
    k_prep_o<<<(NOUTP * CAT) / 256, 256, 0, stream>>>(W2, Wv, Wout);

    void* args[] = {
        (void*)&Wg, (void*)&bg, (void*)&Wzc, (void*)&bfold, (void*)&Wout,
        (void*)&b2, (void*)&bv, (void*)&Dfold, (void*)&xh,
        (void*)&partA, (void*)&partB, (void*)&out, (void*)&bars
    };
    hipLaunchCooperativeKernel((const void*)k_persist, dim3(NBLK), dim3(NTHR),
                               args, 0, stream);
}